// Round 1
// baseline (954.370 us; speedup 1.0000x reference)
//
#include <hip/hip_runtime.h>
#include <hip/hip_fp16.h>

#define BATCH 2048
#define NCAP  1568
#define EDIM  8
#define CD    48      // C*D = 3*16

// ------------------------- K1: u = W@x (fp16), s1 = sum_n u -------------------------
// grid 512 (= B/4), block 128 = 32 n-lanes x 2 cd-halves x 2 g-slots.
// Each thread: 2 batches (gs, gs+2), 24 of 48 cd values, one n per 32-wide tile.
#define K1_THREADS 128
#define K1_TILE    32
#define K1_WROW    388   // padded W row stride in dwords: 384 payload + 4 pad (16B-aligned, bank-stride 4)

__global__ __launch_bounds__(K1_THREADS)
void k1_compute_u(const float* __restrict__ x, const float* __restrict__ W,
                  __half* __restrict__ u, float* __restrict__ s1)
{
    __shared__ float wlds[K1_TILE * K1_WROW];   // 49,664 B
    const int t  = threadIdx.x;
    const int nl = t & 31;
    const int h  = (t >> 5) & 1;   // cd half: [24h, 24h+24)
    const int gs = t >> 6;         // 0..1
    const int bbase = blockIdx.x * 4;
    const int bA = bbase + gs;
    const int bB = bbase + gs + 2;

    float s1a[24], s1b[24];
#pragma unroll
    for (int i = 0; i < 24; ++i) { s1a[i] = 0.f; s1b[i] = 0.f; }

    for (int tile = 0; tile < NCAP / K1_TILE; ++tile) {
        const int n0 = tile * K1_TILE;
        __syncthreads();   // protect previous tile's wlds reads
        // stage W[c, n0..n0+31, :, :] -> wlds[j][c*128 + d*8 + e], padded rows
        for (int id = t; id < 3072; id += K1_THREADS) {
            const int c = id >> 10;
            const int j = (id >> 5) & 31;
            const int q = id & 31;
            const float4 v = *(const float4*)(W + (((size_t)(c * NCAP + n0 + j)) << 7) + (q << 2));
            *(float4*)(wlds + j * K1_WROW + c * 128 + (q << 2)) = v;
        }
        __syncthreads();

        const int n = n0 + nl;
        const float4* xa = (const float4*)(x + ((size_t)bA * NCAP + n) * EDIM);
        const float4* xb = (const float4*)(x + ((size_t)bB * NCAP + n) * EDIM);
        const float4 xa0 = xa[0], xa1 = xa[1];
        const float4 xb0 = xb[0], xb1 = xb[1];

        const float* wrow = wlds + nl * K1_WROW + h * 192;   // 24 cd * 8 e per half
        __half2 uA[12], uB[12];
#pragma unroll
        for (int p = 0; p < 12; ++p) {  // cd pair (2p, 2p+1) within this half
            const float4 w0 = *(const float4*)(wrow + 16 * p);
            const float4 w1 = *(const float4*)(wrow + 16 * p + 4);
            const float4 w2 = *(const float4*)(wrow + 16 * p + 8);
            const float4 w3 = *(const float4*)(wrow + 16 * p + 12);
            const float a0 = w0.x*xa0.x + w0.y*xa0.y + w0.z*xa0.z + w0.w*xa0.w
                           + w1.x*xa1.x + w1.y*xa1.y + w1.z*xa1.z + w1.w*xa1.w;
            const float a1 = w2.x*xa0.x + w2.y*xa0.y + w2.z*xa0.z + w2.w*xa0.w
                           + w3.x*xa1.x + w3.y*xa1.y + w3.z*xa1.z + w3.w*xa1.w;
            const float c0 = w0.x*xb0.x + w0.y*xb0.y + w0.z*xb0.z + w0.w*xb0.w
                           + w1.x*xb1.x + w1.y*xb1.y + w1.z*xb1.z + w1.w*xb1.w;
            const float c1 = w2.x*xb0.x + w2.y*xb0.y + w2.z*xb0.z + w2.w*xb0.w
                           + w3.x*xb1.x + w3.y*xb1.y + w3.z*xb1.z + w3.w*xb1.w;
            s1a[2*p] += a0; s1a[2*p+1] += a1;
            s1b[2*p] += c0; s1b[2*p+1] += c1;
            uA[p] = __floats2half2_rn(a0, a1);
            uB[p] = __floats2half2_rn(c0, c1);
        }
        {
            float4* dA = (float4*)(u + ((size_t)bA * NCAP + n) * CD + h * 24);
            float4* dB = (float4*)(u + ((size_t)bB * NCAP + n) * CD + h * 24);
            const float4* sA = (const float4*)uA;
            const float4* sB = (const float4*)uB;
            dA[0] = sA[0]; dA[1] = sA[1]; dA[2] = sA[2];
            dB[0] = sB[0]; dB[1] = sB[1]; dB[2] = sB[2];
        }
    }

    // reduce s1 across the 32 n-lanes (butterfly allreduce within 32-lane groups)
#pragma unroll
    for (int i = 0; i < 24; ++i) {
        float va = s1a[i], vb = s1b[i];
#pragma unroll
        for (int m = 16; m >= 1; m >>= 1) {
            va += __shfl_xor(va, m, 32);
            vb += __shfl_xor(vb, m, 32);
        }
        s1a[i] = va; s1b[i] = vb;
    }
    if (nl == 0) {
#pragma unroll
        for (int i = 0; i < 24; ++i) {
            s1[bA * CD + h * 24 + i] = s1a[i];
            s1[bB * CD + h * 24 + i] = s1b[i];
        }
    }
}

// ------------------------- K2: routing (2 fused passes, u[b] cached in LDS) -------------------------
#define K2_THREADS 512

__device__ __forceinline__
void block_reduce48(float* acc, float (*sred)[CD], float* stmp, int t)
{
#pragma unroll
    for (int i = 0; i < CD; ++i) {
        float v = acc[i];
        v += __shfl_xor(v, 32); v += __shfl_xor(v, 16); v += __shfl_xor(v, 8);
        v += __shfl_xor(v, 4);  v += __shfl_xor(v, 2);  v += __shfl_xor(v, 1);
        acc[i] = v;
    }
    if ((t & 63) == 0) {
        const int w = t >> 6;
#pragma unroll
        for (int i = 0; i < CD; ++i) sred[w][i] = acc[i];
    }
    __syncthreads();
    if (t < CD) {
        float s = 0.f;
#pragma unroll
        for (int w = 0; w < K2_THREADS / 64; ++w) s += sred[w][t];
        stmp[t] = s;
    }
    __syncthreads();
}

__global__ __launch_bounds__(K2_THREADS)
void k2_routing(const __half* __restrict__ u, const float* __restrict__ s1,
                float* __restrict__ out)
{
    __shared__ __half ulds[NCAP * CD];          // 150,528 B
    __shared__ float  sred[K2_THREADS / 64][CD];
    __shared__ float  stmp[CD];
    __shared__ float  vv1[CD];
    __shared__ float  vv2[CD];

    const int t = threadIdx.x;
    const int b = blockIdx.x;

    // v1 = squash(s1/3)
    if (t < CD) stmp[t] = s1[b * CD + t] * (1.0f / 3.0f);
    __syncthreads();
    if (t < CD) {
        const int c = t >> 4;
        float sq = 0.f;
#pragma unroll
        for (int d = 0; d < 16; ++d) { const float z = stmp[c * 16 + d]; sq += z * z; }
        vv1[t] = stmp[t] * (sqrtf(sq) / (1.f + sq));
    }
    __syncthreads();

    const __half* ub = u + (size_t)b * NCAP * CD;
    float acc[CD];
#pragma unroll
    for (int i = 0; i < CD; ++i) acc[i] = 0.f;

    // ---- pass A: stream u from HBM -> LDS; logits d1 = v1.u; s2 = sum softmax(d1).u
    for (int n = t; n < NCAP; n += K2_THREADS) {
        float4 rr[6];
        const float4* src = (const float4*)(ub + (size_t)n * CD);
#pragma unroll
        for (int k = 0; k < 6; ++k) rr[k] = src[k];
        float4* dst = (float4*)(ulds + (size_t)n * CD);
#pragma unroll
        for (int k = 0; k < 6; ++k) dst[k] = rr[k];
        const __half2* hp = (const __half2*)rr;
        float dl0 = 0.f, dl1 = 0.f, dl2 = 0.f;
#pragma unroll
        for (int i = 0; i < 24; ++i) {
            const float2 f = __half22float2(hp[i]);
            const int cd = 2 * i;
            const float q = vv1[cd] * f.x + vv1[cd + 1] * f.y;
            if (cd < 16) dl0 += q; else if (cd < 32) dl1 += q; else dl2 += q;
        }
        const float m  = fmaxf(dl0, fmaxf(dl1, dl2));
        const float e0 = __expf(dl0 - m), e1 = __expf(dl1 - m), e2 = __expf(dl2 - m);
        const float inv = 1.f / (e0 + e1 + e2);
        const float cc0 = e0 * inv, cc1 = e1 * inv, cc2 = e2 * inv;
#pragma unroll
        for (int i = 0; i < 24; ++i) {
            const float2 f = __half22float2(hp[i]);
            const int cd = 2 * i;
            const float cc = (cd < 16) ? cc0 : ((cd < 32) ? cc1 : cc2);
            acc[cd]     += cc * f.x;
            acc[cd + 1] += cc * f.y;
        }
    }
    block_reduce48(acc, sred, stmp, t);  // stmp = s2 (ends with barrier; also fences ulds)
    if (t < CD) {
        const int c = t >> 4;
        float sq = 0.f;
#pragma unroll
        for (int d = 0; d < 16; ++d) { const float z = stmp[c * 16 + d]; sq += z * z; }
        vv2[t] = stmp[t] * (sqrtf(sq) / (1.f + sq));
    }
    __syncthreads();

    // ---- pass B: u from LDS; logits = (v1+v2).u; s3 = sum softmax.u
#pragma unroll
    for (int i = 0; i < CD; ++i) acc[i] = 0.f;
    for (int n = t; n < NCAP; n += K2_THREADS) {
        float4 rr[6];
        const float4* src = (const float4*)(ulds + (size_t)n * CD);
#pragma unroll
        for (int k = 0; k < 6; ++k) rr[k] = src[k];
        const __half2* hp = (const __half2*)rr;
        float dl0 = 0.f, dl1 = 0.f, dl2 = 0.f;
#pragma unroll
        for (int i = 0; i < 24; ++i) {
            const float2 f = __half22float2(hp[i]);
            const int cd = 2 * i;
            const float q = (vv1[cd] + vv2[cd]) * f.x + (vv1[cd + 1] + vv2[cd + 1]) * f.y;
            if (cd < 16) dl0 += q; else if (cd < 32) dl1 += q; else dl2 += q;
        }
        const float m  = fmaxf(dl0, fmaxf(dl1, dl2));
        const float e0 = __expf(dl0 - m), e1 = __expf(dl1 - m), e2 = __expf(dl2 - m);
        const float inv = 1.f / (e0 + e1 + e2);
        const float cc0 = e0 * inv, cc1 = e1 * inv, cc2 = e2 * inv;
#pragma unroll
        for (int i = 0; i < 24; ++i) {
            const float2 f = __half22float2(hp[i]);
            const int cd = 2 * i;
            const float cc = (cd < 16) ? cc0 : ((cd < 32) ? cc1 : cc2);
            acc[cd]     += cc * f.x;
            acc[cd + 1] += cc * f.y;
        }
    }
    block_reduce48(acc, sred, stmp, t);  // stmp = s3
    if (t < CD) {
        const int c = t >> 4;
        float sq = 0.f;
#pragma unroll
        for (int d = 0; d < 16; ++d) { const float z = stmp[c * 16 + d]; sq += z * z; }
        out[b * CD + t] = stmp[t] * (sqrtf(sq) / (1.f + sq));
    }
}

extern "C" void kernel_launch(void* const* d_in, const int* in_sizes, int n_in,
                              void* d_out, int out_size, void* d_ws, size_t ws_size,
                              hipStream_t stream) {
    (void)in_sizes; (void)n_in; (void)out_size;
    const float* x = (const float*)d_in[0];          // (B, N, E) fp32
    const float* W = (const float*)d_in[1];          // (1, C, N, D, E) fp32
    const size_t u_bytes = (size_t)BATCH * NCAP * CD * sizeof(__half);   // 308,281,344
    const size_t need    = u_bytes + (size_t)BATCH * CD * sizeof(float); // + 393,216
    if (ws_size < need) return;   // ws too small — fail cleanly (learn ws_size from bench)

    __half* u  = (__half*)d_ws;
    float*  s1 = (float*)((char*)d_ws + u_bytes);
    float*  out = (float*)d_out;

    hipLaunchKernelGGL(k1_compute_u, dim3(BATCH / 4), dim3(K1_THREADS), 0, stream, x, W, u, s1);
    hipLaunchKernelGGL(k2_routing,   dim3(BATCH),     dim3(K2_THREADS), 0, stream, u, s1, out);
}

// Round 2
// 686.746 us; speedup vs baseline: 1.3897x; 1.3897x over previous
//
#include <hip/hip_runtime.h>

#define BB 2048
#define NN 1568
#define CD 48
#define NCHUNK 98          // n-chunks of 16; 98*16 = 1568
#define BGROUPS 64         // batch groups of 32; 64*32 = 2048

// ---------------- pass kernel: one wave per block, no LDS, no barriers ----------------
// lane l: bl = l&31 (batch within group), h = l>>5 (d-half: d in [h*8, h*8+8))
// block: (bg, g) -> batches [bg*32, bg*32+32), n in [g*16, g*16+16)
// PASS 0: partial[g][b][cd] = sum_n u[b,n,cd]
// PASS 1/2: partial = sum_n softmax_c(vin . u) * u
template<int PASS>
__global__ __launch_bounds__(64, 4)
void caps_pass(const float* __restrict__ x, const float* __restrict__ W,
               const float* __restrict__ vin, float* __restrict__ part)
{
    const int l  = threadIdx.x;
    const int bl = l & 31;
    const int h  = l >> 5;
    const int bg = blockIdx.x & 63;
    const int g  = blockIdx.x >> 6;
    const int b  = bg * 32 + bl;
    const int n0 = g * 16;

    // per-lane routing vector (24 of 48 entries: c*8+dd <-> cd = c*16 + h*8 + dd)
    float vv[24];
    if (PASS > 0) {
#pragma unroll
        for (int c = 0; c < 3; ++c) {
            const float4 a = __ldg((const float4*)(vin + b * CD + c * 16 + h * 8));
            const float4 q = __ldg((const float4*)(vin + b * CD + c * 16 + h * 8 + 4));
            vv[c*8+0]=a.x; vv[c*8+1]=a.y; vv[c*8+2]=a.z; vv[c*8+3]=a.w;
            vv[c*8+4]=q.x; vv[c*8+5]=q.y; vv[c*8+6]=q.z; vv[c*8+7]=q.w;
        }
    }

    float acc[24];
#pragma unroll
    for (int j = 0; j < 24; ++j) acc[j] = 0.f;

    for (int i = 0; i < 16; ++i) {
        const int n = n0 + i;
        const float4 x0 = __ldg((const float4*)(x + ((size_t)b * NN + n) * 8));
        const float4 x1 = __ldg((const float4*)(x + ((size_t)b * NN + n) * 8 + 4));

        float U[24];
#pragma unroll
        for (int c = 0; c < 3; ++c) {
            const float* wb = W + ((size_t)(c * NN + n)) * 128 + h * 64;
#pragma unroll
            for (int d = 0; d < 8; ++d) {
                const float4 w0 = __ldg((const float4*)(wb + d * 8));
                const float4 w1 = __ldg((const float4*)(wb + d * 8 + 4));
                U[c*8+d] = w0.x*x0.x + w0.y*x0.y + w0.z*x0.z + w0.w*x0.w
                         + w1.x*x1.x + w1.y*x1.y + w1.z*x1.z + w1.w*x1.w;
            }
        }

        if (PASS == 0) {
#pragma unroll
            for (int j = 0; j < 24; ++j) acc[j] += U[j];
        } else {
            float lp0 = 0.f, lp1 = 0.f, lp2 = 0.f;
#pragma unroll
            for (int d = 0; d < 8; ++d) {
                lp0 += vv[d]      * U[d];
                lp1 += vv[8 + d]  * U[8 + d];
                lp2 += vv[16 + d] * U[16 + d];
            }
            // combine the two d-halves (lane ^ 32 holds the other half, same batch)
            const float l0 = lp0 + __shfl_xor(lp0, 32);
            const float l1 = lp1 + __shfl_xor(lp1, 32);
            const float l2 = lp2 + __shfl_xor(lp2, 32);
            const float mx = fmaxf(l0, fmaxf(l1, l2));
            const float e0 = __expf(l0 - mx), e1 = __expf(l1 - mx), e2 = __expf(l2 - mx);
            const float inv = 1.f / (e0 + e1 + e2);
            const float c0 = e0 * inv, c1 = e1 * inv, c2 = e2 * inv;
#pragma unroll
            for (int d = 0; d < 8; ++d) {
                acc[d]      += c0 * U[d];
                acc[8 + d]  += c1 * U[8 + d];
                acc[16 + d] += c2 * U[16 + d];
            }
        }
    }

    // store partials: part[g][b][c*16 + h*8 + dd]
    float* pb = part + ((size_t)g * BB + b) * CD + h * 8;
#pragma unroll
    for (int c = 0; c < 3; ++c) {
        float4 s0, s1;
        s0.x = acc[c*8+0]; s0.y = acc[c*8+1]; s0.z = acc[c*8+2]; s0.w = acc[c*8+3];
        s1.x = acc[c*8+4]; s1.y = acc[c*8+5]; s1.z = acc[c*8+6]; s1.w = acc[c*8+7];
        *(float4*)(pb + c * 16)     = s0;
        *(float4*)(pb + c * 16 + 4) = s1;
    }
}

// ---------------- reduce kernel: s = sum_g part; squash; emit v ----------------
// MODE 1: vout = squash(s/3)              (v1)
// MODE 2: vout = squash(s) + vin          (w2 = v1 + v2)
// MODE 3: vout = squash(s)                (final output)
template<int MODE>
__global__ __launch_bounds__(256, 4)
void caps_reduce(const float* __restrict__ part, const float* __restrict__ vin,
                 float* __restrict__ vout)
{
    const int t = blockIdx.x * 256 + threadIdx.x;   // 0 .. B*CD-1
    float s = 0.f;
#pragma unroll 7
    for (int g = 0; g < NCHUNK; ++g) s += part[(size_t)g * (BB * CD) + t];
    if (MODE == 1) s *= (1.0f / 3.0f);
    // squash over the 16 d of this (b,c): threads t..t+15 share (b,c), d = t%16
    float q = s * s;
#pragma unroll
    for (int m = 1; m < 16; m <<= 1) q += __shfl_xor(q, m);
    float v = s * sqrtf(q) / (1.f + q);
    if (MODE == 2) v += __ldg(vin + t);
    vout[t] = v;
}

extern "C" void kernel_launch(void* const* d_in, const int* in_sizes, int n_in,
                              void* d_out, int out_size, void* d_ws, size_t ws_size,
                              hipStream_t stream) {
    (void)in_sizes; (void)n_in; (void)out_size;
    const float* x = (const float*)d_in[0];   // (B, N, 8) fp32
    const float* W = (const float*)d_in[1];   // (1, 3, N, 16, 8) fp32

    const size_t part_bytes = (size_t)NCHUNK * BB * CD * sizeof(float);  // 38,535,168
    float* part = (float*)d_ws;
    float* v1   = (float*)((char*)d_ws + part_bytes);
    float* w2   = v1 + BB * CD;
    float* out  = (float*)d_out;
    if (ws_size < part_bytes + 2 * BB * CD * sizeof(float)) return;

    const dim3 pg(BGROUPS * NCHUNK), pb(64);
    const dim3 rg((BB * CD) / 256), rb(256);

    hipLaunchKernelGGL(caps_pass<0>,   pg, pb, 0, stream, x, W, nullptr, part);
    hipLaunchKernelGGL(caps_reduce<1>, rg, rb, 0, stream, part, nullptr, v1);
    hipLaunchKernelGGL(caps_pass<1>,   pg, pb, 0, stream, x, W, v1, part);
    hipLaunchKernelGGL(caps_reduce<2>, rg, rb, 0, stream, part, v1, w2);
    hipLaunchKernelGGL(caps_pass<2>,   pg, pb, 0, stream, x, W, w2, part);
    hipLaunchKernelGGL(caps_reduce<3>, rg, rb, 0, stream, part, nullptr, out);
}